// Round 13
// baseline (76.903 us; speedup 1.0000x reference)
//
#include <hip/hip_runtime.h>

// Loss_net: neural-ODE loss forward. R=8192 samples, D=3, N=10 super-steps.
// 16 lanes per sample-pair, 2 unit-tasks per lane, 2 samples per thread (ILP).
// Round 13: single-kernel (finalize fused). Each block release-stores its
// partials + a MAGIC flag into d_ws; block 255 acquire-spins on the 256 flags,
// reduces, writes out[0..3], then resets flags to 0. Works from ANY initial
// ws state (poison 0xAA.. != MAGIC, 0 != MAGIC); flags are always reset, so
// repeated launches are safe even without re-poisoning. No cross-block
// circular wait; 256 blocks x 256 threads = 1 block/CU (co-resident).

#define R_    8192
#define N_    10
#define H_    0.1f
#define H6_   0.0166666666667f    // H/6
#define MAGIC 0x5EEDFACEu

__device__ __forceinline__ float fast_tanh(float x) {
    // tanh(x) = 1 - 2/(exp(2x)+1); exp via hw exp2, rcp via hw rcp (~1e-7 rel err)
    float e = __builtin_amdgcn_exp2f(x * 2.8853900817779268f); // 2*log2(e)*x
    return fmaf(-2.0f, __builtin_amdgcn_rcpf(e + 1.0f), 1.0f);
}

// --- DPP butterfly add over 16 contiguous lanes (all lanes get the sum) ---
template<int CTRL>
__device__ __forceinline__ float dpp_addf(float v) {
    int t = __builtin_amdgcn_update_dpp(0, __float_as_int(v), CTRL, 0xF, 0xF, true);
    return v + __int_as_float(t);
}
__device__ __forceinline__ float red16(float v) {
    v = dpp_addf<0xB1>(v);    // quad_perm xor1
    v = dpp_addf<0x4E>(v);    // quad_perm xor2
    v = dpp_addf<0x141>(v);   // row_half_mirror (xor within 8)
    v = dpp_addf<0x140>(v);   // row_mirror (crosses the two 8-halves)
    return v;
}

struct WReg {
    float w1[2][3];
    float b1v[2];
    float w2[2][3];
    float b2v[3];
};

// Pure loads for one step's weights (shared by both samples). Offsets are
// per-lane constants; base pointers advance per step.
__device__ __forceinline__ void load_step(WReg& W,
        const float* __restrict__ pW1, const float* __restrict__ pB1,
        const float* __restrict__ pW2, const float* __restrict__ pB2,
        int o1a, int o1b, int oba, int obb, int o2a, int o2b, int ob2,
        bool padB, bool ab2) {
    W.w1[0][0] = pW1[o1a];     W.w1[0][1] = pW1[o1a + 1]; W.w1[0][2] = pW1[o1a + 2];
    W.w1[1][0] = pW1[o1b];     W.w1[1][1] = pW1[o1b + 1]; W.w1[1][2] = pW1[o1b + 2];
    W.b1v[0]   = pB1[oba];     W.b1v[1]   = pB1[obb];
    W.w2[0][0] = pW2[o2a];     W.w2[0][1] = pW2[o2a + 5]; W.w2[0][2] = pW2[o2a + 10];
    float w2b0 = pW2[o2b],     w2b1 = pW2[o2b + 5],       w2b2 = pW2[o2b + 10];
    W.w2[1][0] = padB ? 0.0f : w2b0;
    W.w2[1][1] = padB ? 0.0f : w2b1;
    W.w2[1][2] = padB ? 0.0f : w2b2;
    float b20 = pB2[ob2], b21 = pB2[ob2 + 1], b22 = pB2[ob2 + 2];
    W.b2v[0] = ab2 ? b20 : 0.0f;
    W.b2v[1] = ab2 ? b21 : 0.0f;
    W.b2v[2] = ab2 ? b22 : 0.0f;
}

// paired fused v + divergence: v reduced; div returned as UNREDUCED lane partials.
__device__ __forceinline__ void v_div_eval2(const WReg& W, float p, float g0, float g1,
        float xa0, float xa1, float xa2, float xb0, float xb1, float xb2,
        float& va0, float& va1, float& va2, float& vb0, float& vb1, float& vb2,
        float& dA, float& dB) {
    float pA0 = fmaf(W.w1[0][0], xa0, fmaf(W.w1[0][1], xa1, fmaf(W.w1[0][2], xa2, W.b1v[0])));
    float pB0 = fmaf(W.w1[0][0], xb0, fmaf(W.w1[0][1], xb1, fmaf(W.w1[0][2], xb2, W.b1v[0])));
    float pA1 = fmaf(W.w1[1][0], xa0, fmaf(W.w1[1][1], xa1, fmaf(W.w1[1][2], xa2, W.b1v[1])));
    float pB1 = fmaf(W.w1[1][0], xb0, fmaf(W.w1[1][1], xb1, fmaf(W.w1[1][2], xb2, W.b1v[1])));
    float aA0 = fast_tanh(pA0);
    float aB0 = fast_tanh(pB0);
    float aA1 = fast_tanh(pA1);
    float aB1 = fast_tanh(pB1);
    float yA0 = fmaf(W.w2[0][0], aA0, fmaf(W.w2[1][0], aA1, W.b2v[0]));
    float yB0 = fmaf(W.w2[0][0], aB0, fmaf(W.w2[1][0], aB1, W.b2v[0]));
    float yA1 = fmaf(W.w2[0][1], aA0, fmaf(W.w2[1][1], aA1, W.b2v[1]));
    float yB1 = fmaf(W.w2[0][1], aB0, fmaf(W.w2[1][1], aB1, W.b2v[1]));
    float yA2 = fmaf(W.w2[0][2], aA0, fmaf(W.w2[1][2], aA1, W.b2v[2]));
    float yB2 = fmaf(W.w2[0][2], aB0, fmaf(W.w2[1][2], aB1, W.b2v[2]));
    float uA0 = fmaf(-aA0, aA0, 1.0f), uA1 = fmaf(-aA1, aA1, 1.0f);
    float uB0 = fmaf(-aB0, aB0, 1.0f), uB1 = fmaf(-aB1, aB1, 1.0f);
    float sA = fmaf(g0, uA0, g1 * uA1);
    float sB = fmaf(g0, uB0, g1 * uB1);
    va0 = red16(p * yA0); vb0 = red16(p * yB0);
    va1 = red16(p * yA1); vb1 = red16(p * yB1);
    va2 = red16(p * yA2); vb2 = red16(p * yB2);
    dA = p * sA; dB = p * sB;
}

// One full super-step: RK2 midpoint with fused mid/node v+div. 2 paired evals.
__device__ __forceinline__ void compute_step2(const WReg& W,
        float p12, float p1,
        float& XA0, float& XA1, float& XA2, float& XB0, float& XB1, float& XB2,
        float& vAa0, float& vAa1, float& vAa2, float& vAb0, float& vAb1, float& vAb2,
        float& dpA, float& dpB, float& div_acc, float& loss1p) {
    float g0 = fmaf(W.w2[0][0], W.w1[0][0], fmaf(W.w2[0][1], W.w1[0][1], W.w2[0][2] * W.w1[0][2]));
    float g1 = fmaf(W.w2[1][0], W.w1[1][0], fmaf(W.w2[1][1], W.w1[1][1], W.w2[1][2] * W.w1[1][2]));
    const float hh = H_ * 0.5f;

    // mid eval (fused v+div) at the RK2 stage state X0 + H/2*vA: vB = K2, d_mid
    float vBa0, vBa1, vBa2, vBb0, vBb1, vBb2, dmA, dmB;
    v_div_eval2(W, p12, g0, g1,
                fmaf(hh, vAa0, XA0), fmaf(hh, vAa1, XA1), fmaf(hh, vAa2, XA2),
                fmaf(hh, vAb0, XB0), fmaf(hh, vAb1, XB1), fmaf(hh, vAb2, XB2),
                vBa0, vBa1, vBa2, vBb0, vBb1, vBb2, dmA, dmB);
    // midpoint method: X1 = X0 + H*K2
    XA0 = fmaf(H_, vBa0, XA0);
    XA1 = fmaf(H_, vBa1, XA1);
    XA2 = fmaf(H_, vBa2, XA2);
    XB0 = fmaf(H_, vBb0, XB0);
    XB1 = fmaf(H_, vBb1, XB1);
    XB2 = fmaf(H_, vBb2, XB2);

    // node eval (fused v+div) at (X1, tn+H): vC, d_end; vC also = next step's K1
    float vCa0, vCa1, vCa2, vCb0, vCb1, vCb2, deA, deB;
    v_div_eval2(W, p1, g0, g1, XA0, XA1, XA2, XB0, XB1, XB2,
                vCa0, vCa1, vCa2, vCb0, vCb1, vCb2, deA, deB);

    // Simpson for lnRo over [tn, tn+H] (scaled by -H/6 at the end)
    div_acc += (dpA + 4.0f * dmA + deA) + (dpB + 4.0f * dmB + deB);
    dpA = deA; dpB = deB;                      // = d0 of next step
    loss1p += (vAa0 * vAa0 + vAa1 * vAa1 + vAa2 * vAa2)
            + 4.0f * (vBa0 * vBa0 + vBa1 * vBa1 + vBa2 * vBa2)
            + (vCa0 * vCa0 + vCa1 * vCa1 + vCa2 * vCa2)
            + (vAb0 * vAb0 + vAb1 * vAb1 + vAb2 * vAb2)
            + 4.0f * (vBb0 * vBb0 + vBb1 * vBb1 + vBb2 * vBb2)
            + (vCb0 * vCb0 + vCb1 * vCb1 + vCb2 * vCb2);
    vAa0 = vCa0; vAa1 = vCa1; vAa2 = vCa2;
    vAb0 = vCb0; vAb1 = vCb1; vAb2 = vCb2;
}

__global__ void __launch_bounds__(256)
loss_fused_kernel(const float* __restrict__ x,
                  const float* __restrict__ W1, const float* __restrict__ b1,
                  const float* __restrict__ W2, const float* __restrict__ b2,
                  double* __restrict__ dws, float* __restrict__ out) {
    int gid = blockIdx.x * blockDim.x + threadIdx.x;
    int rA  = gid >> 4;       // sample A; sample B = rA + 4096
    int sub = gid & 15;
    int ii  = sub >> 3;       // basis half: 0 -> basis k, 1 -> basis k+1
    int j   = sub & 7;        // unit-tasks {2j, 2j+1}

    // ---- per-lane constant task offsets (within a step's 3-block window)
    int tauA = 2 * j, tauB = 2 * j + 1;
    bool padB = (tauB >= 15);
    int tB  = padB ? 0 : tauB;
    int lA  = tauA / 5, hA = tauA - 5 * lA;
    int lB  = tB / 5,   hB = tB - 5 * lB;
    int bA  = ii * 3 + lA, bB = ii * 3 + lB;
    int o1a = bA * 15 + hA * 3, o1b = bB * 15 + hB * 3;
    int oba = bA * 5 + hA,      obb = bB * 5 + hB;
    int o2a = bA * 15 + hA,     o2b = bB * 15 + hB;
    bool ab2 = (j < 3);
    int ob2 = (ii * 3 + (ab2 ? j : 0)) * 3;

    // ---- hat-basis weights: exact per-eval constants (w = 10t - k)
    float iif = (float)ii;
    float p12 = 0.5f;
    float p1  = iif;
    float p0  = 1.0f - iif;

    float XA0 = x[rA * 3 + 0], XA1 = x[rA * 3 + 1], XA2 = x[rA * 3 + 2];
    int rB = rA + 4096;
    float XB0 = x[rB * 3 + 0], XB1 = x[rB * 3 + 1], XB2 = x[rB * 3 + 2];

    float klbase = -0.5f * (XA0 * XA0 + XA1 * XA1 + XA2 * XA2)
                 - 0.5f * (XB0 * XB0 + XB1 * XB1 + XB2 * XB2);  // lnRo0 minus const
    float loss1p = 0.0f, div_acc = 0.0f;

    const float* pW1 = W1;
    const float* pB1 = b1;
    const float* pW2 = W2;
    const float* pB2 = b2;

    WReg A, B;
    load_step(A, pW1, pB1, pW2, pB2, o1a, o1b, oba, obb, o2a, o2b, ob2, padB, ab2);

    // initial eval at t=0: vA (reduced) + d0 partials
    float g0A = fmaf(A.w2[0][0], A.w1[0][0], fmaf(A.w2[0][1], A.w1[0][1], A.w2[0][2] * A.w1[0][2]));
    float g1A = fmaf(A.w2[1][0], A.w1[1][0], fmaf(A.w2[1][1], A.w1[1][1], A.w2[1][2] * A.w1[1][2]));
    float vAa0, vAa1, vAa2, vAb0, vAb1, vAb2, dpA, dpB;
    v_div_eval2(A, p0, g0A, g1A, XA0, XA1, XA2, XB0, XB1, XB2,
                vAa0, vAa1, vAa2, vAb0, vAb1, vAb2, dpA, dpB);

    #pragma unroll 1
    for (int kk = 0; kk < 5; ++kk) {
        // prefetch step 2kk+1 into B
        load_step(B, pW1 + 45, pB1 + 15, pW2 + 45, pB2 + 9,
                  o1a, o1b, oba, obb, o2a, o2b, ob2, padB, ab2);
        compute_step2(A, p12, p1,
                      XA0, XA1, XA2, XB0, XB1, XB2,
                      vAa0, vAa1, vAa2, vAb0, vAb1, vAb2,
                      dpA, dpB, div_acc, loss1p);
        // prefetch step 2kk+2 into A (last iter: harmless reload of step 9)
        const float* qW1 = pW1 + ((kk < 4) ? 90 : 45);
        const float* qB1 = pB1 + ((kk < 4) ? 30 : 15);
        const float* qW2 = pW2 + ((kk < 4) ? 90 : 45);
        const float* qB2 = pB2 + ((kk < 4) ? 18 : 9);
        load_step(A, qW1, qB1, qW2, qB2,
                  o1a, o1b, oba, obb, o2a, o2b, ob2, padB, ab2);
        compute_step2(B, p12, p1,
                      XA0, XA1, XA2, XB0, XB1, XB2,
                      vAa0, vAa1, vAa2, vAb0, vAb1, vAb2,
                      dpA, dpB, div_acc, loss1p);
        pW1 += 90; pB1 += 30; pW2 += 90; pB2 += 18;
    }

    // KL per sample-pair: (lnRo0 - lnr1) terms; the 3*log(2pi) constants cancel.
    float eA0 = XA0 - 1.0f, eA1 = XA1 - 1.0f, eA2 = XA2 - 1.0f;
    float eB0 = XB0 - 1.0f, eB1 = XB1 - 1.0f, eB2 = XB2 - 1.0f;
    float lnr1 = -0.5f * (eA0 * eA0 + eA1 * eA1 + eA2 * eA2)
               - 0.5f * (eB0 * eB0 + eB1 * eB1 + eB2 * eB2);
    float klp = ((threadIdx.x & 15) == 0) ? (klbase - lnr1) : 0.0f;
    klp = fmaf(-H6_, div_acc, klp);
    if ((threadIdx.x & 15) != 0) loss1p = 0.0f;

    #pragma unroll
    for (int off = 1; off < 64; off <<= 1) {    // once per kernel: shfl is fine here
        loss1p += __shfl_xor(loss1p, off);
        klp    += __shfl_xor(klp, off);
    }

    // ---- block partial: 4 wave partials -> 1 via LDS
    __shared__ double wl1[4], wkl[4];
    __shared__ double bl1[4], bkl[4];     // separate arrays for phase 2 (no WAR race)
    int wv = threadIdx.x >> 6;
    if ((threadIdx.x & 63) == 0) { wl1[wv] = (double)loss1p; wkl[wv] = (double)klp; }
    __syncthreads();

    unsigned int* flags = (unsigned int*)(dws + 512);
    if (threadIdx.x == 0) {
        double L1 = wl1[0] + wl1[1] + wl1[2] + wl1[3];
        double KL = wkl[0] + wkl[1] + wkl[2] + wkl[3];
        dws[blockIdx.x]       = L1;
        dws[256 + blockIdx.x] = KL;
        __threadfence();   // device-scope: partials visible before flag
        __hip_atomic_store(&flags[blockIdx.x], MAGIC, __ATOMIC_RELEASE,
                           __HIP_MEMORY_SCOPE_AGENT);
    }

    // ---- block 255 gathers all partials and finalizes
    if (blockIdx.x == 255) {
        int t = threadIdx.x;
        while (__hip_atomic_load(&flags[t], __ATOMIC_ACQUIRE,
                                 __HIP_MEMORY_SCOPE_AGENT) != MAGIC) {
            __builtin_amdgcn_s_sleep(1);
        }
        double l1 = dws[t];
        double kl = dws[256 + t];
        #pragma unroll
        for (int off = 1; off < 64; off <<= 1) {
            l1 += __shfl_xor(l1, off);
            kl += __shfl_xor(kl, off);
        }
        __syncthreads();   // ensure thread 0's phase-1 LDS reads are done everywhere
        if ((t & 63) == 0) { bl1[t >> 6] = l1; bkl[t >> 6] = kl; }
        __syncthreads();
        if (t == 0) {
            double L1 = bl1[0] + bl1[1] + bl1[2] + bl1[3];
            double KL = bkl[0] + bkl[1] + bkl[2] + bkl[3];
            double l1s = (double)H_ / (6.0 * (double)R_) * L1;
            double kls = KL / (double)R_;   // 3*log(2pi) constants canceled exactly
            float l1f = (float)l1s;
            float klf = (float)kls;
            out[0] = l1f + klf;   // loss  (loss_F == 0)
            out[1] = l1f;         // loss1
            out[2] = klf;         // loss_KL
            out[3] = 0.0f;        // loss_F
        }
        // reset flags so any future launch starts from a non-MAGIC state
        __hip_atomic_store(&flags[t], 0u, __ATOMIC_RELAXED,
                           __HIP_MEMORY_SCOPE_AGENT);
    }
}

extern "C" void kernel_launch(void* const* d_in, const int* in_sizes, int n_in,
                              void* d_out, int out_size, void* d_ws, size_t ws_size,
                              hipStream_t stream) {
    const float* x  = (const float*)d_in[0];
    const float* W1 = (const float*)d_in[1];
    const float* b1 = (const float*)d_in[2];
    const float* W2 = (const float*)d_in[3];
    const float* b2 = (const float*)d_in[4];
    double* ws = (double*)d_ws;   // [0..255]=loss1 block partials, [256..511]=KL,
                                  // bytes at dws+512: 256 uint32 flags
    float* out = (float*)d_out;

    // 4096 sample-pairs x 16 lanes = 65536 threads = 256 blocks x 256 (1 block/CU)
    loss_fused_kernel<<<256, 256, 0, stream>>>(x, W1, b1, W2, b2, ws, out);
}

// Round 14
// 72.564 us; speedup vs baseline: 1.0598x; 1.0598x over previous
//
#include <hip/hip_runtime.h>

// Loss_net: neural-ODE loss forward. R=8192 samples, D=3, N=10 super-steps.
// 16 lanes per sample-pair, 2 unit-tasks per lane, 2 samples per thread (ILP).
// REVERT to round-12 structure (best: 71.2us): two kernels. The fused
// spin-wait variant (r13) regressed 5.7us -- cross-XCD flag polling serialized
// the tail. Kernel math: RK2 midpoint + fused v+div at mid/node = 2 paired
// evals/step (Simpson quadrature floor); d_end->d0 node carry; divergence
// accumulated as unreduced lane partials folded into the final wave reduce.

#define R_    8192
#define N_    10
#define H_    0.1f
#define H6_   0.0166666666667f    // H/6
#define NWAVES 1024               // 256 blocks x 256 threads / 64

__device__ __forceinline__ float fast_tanh(float x) {
    // tanh(x) = 1 - 2/(exp(2x)+1); exp via hw exp2, rcp via hw rcp (~1e-7 rel err)
    float e = __builtin_amdgcn_exp2f(x * 2.8853900817779268f); // 2*log2(e)*x
    return fmaf(-2.0f, __builtin_amdgcn_rcpf(e + 1.0f), 1.0f);
}

// --- DPP butterfly add over 16 contiguous lanes (all lanes get the sum) ---
template<int CTRL>
__device__ __forceinline__ float dpp_addf(float v) {
    int t = __builtin_amdgcn_update_dpp(0, __float_as_int(v), CTRL, 0xF, 0xF, true);
    return v + __int_as_float(t);
}
__device__ __forceinline__ float red16(float v) {
    v = dpp_addf<0xB1>(v);    // quad_perm xor1
    v = dpp_addf<0x4E>(v);    // quad_perm xor2
    v = dpp_addf<0x141>(v);   // row_half_mirror (xor within 8)
    v = dpp_addf<0x140>(v);   // row_mirror (crosses the two 8-halves)
    return v;
}

struct WReg {
    float w1[2][3];
    float b1v[2];
    float w2[2][3];
    float b2v[3];
};

// Pure loads for one step's weights (shared by both samples). Offsets are
// per-lane constants; base pointers advance per step.
__device__ __forceinline__ void load_step(WReg& W,
        const float* __restrict__ pW1, const float* __restrict__ pB1,
        const float* __restrict__ pW2, const float* __restrict__ pB2,
        int o1a, int o1b, int oba, int obb, int o2a, int o2b, int ob2,
        bool padB, bool ab2) {
    W.w1[0][0] = pW1[o1a];     W.w1[0][1] = pW1[o1a + 1]; W.w1[0][2] = pW1[o1a + 2];
    W.w1[1][0] = pW1[o1b];     W.w1[1][1] = pW1[o1b + 1]; W.w1[1][2] = pW1[o1b + 2];
    W.b1v[0]   = pB1[oba];     W.b1v[1]   = pB1[obb];
    W.w2[0][0] = pW2[o2a];     W.w2[0][1] = pW2[o2a + 5]; W.w2[0][2] = pW2[o2a + 10];
    float w2b0 = pW2[o2b],     w2b1 = pW2[o2b + 5],       w2b2 = pW2[o2b + 10];
    W.w2[1][0] = padB ? 0.0f : w2b0;
    W.w2[1][1] = padB ? 0.0f : w2b1;
    W.w2[1][2] = padB ? 0.0f : w2b2;
    float b20 = pB2[ob2], b21 = pB2[ob2 + 1], b22 = pB2[ob2 + 2];
    W.b2v[0] = ab2 ? b20 : 0.0f;
    W.b2v[1] = ab2 ? b21 : 0.0f;
    W.b2v[2] = ab2 ? b22 : 0.0f;
}

// paired fused v + divergence: v reduced; div returned as UNREDUCED lane partials.
__device__ __forceinline__ void v_div_eval2(const WReg& W, float p, float g0, float g1,
        float xa0, float xa1, float xa2, float xb0, float xb1, float xb2,
        float& va0, float& va1, float& va2, float& vb0, float& vb1, float& vb2,
        float& dA, float& dB) {
    float pA0 = fmaf(W.w1[0][0], xa0, fmaf(W.w1[0][1], xa1, fmaf(W.w1[0][2], xa2, W.b1v[0])));
    float pB0 = fmaf(W.w1[0][0], xb0, fmaf(W.w1[0][1], xb1, fmaf(W.w1[0][2], xb2, W.b1v[0])));
    float pA1 = fmaf(W.w1[1][0], xa0, fmaf(W.w1[1][1], xa1, fmaf(W.w1[1][2], xa2, W.b1v[1])));
    float pB1 = fmaf(W.w1[1][0], xb0, fmaf(W.w1[1][1], xb1, fmaf(W.w1[1][2], xb2, W.b1v[1])));
    float aA0 = fast_tanh(pA0);
    float aB0 = fast_tanh(pB0);
    float aA1 = fast_tanh(pA1);
    float aB1 = fast_tanh(pB1);
    float yA0 = fmaf(W.w2[0][0], aA0, fmaf(W.w2[1][0], aA1, W.b2v[0]));
    float yB0 = fmaf(W.w2[0][0], aB0, fmaf(W.w2[1][0], aB1, W.b2v[0]));
    float yA1 = fmaf(W.w2[0][1], aA0, fmaf(W.w2[1][1], aA1, W.b2v[1]));
    float yB1 = fmaf(W.w2[0][1], aB0, fmaf(W.w2[1][1], aB1, W.b2v[1]));
    float yA2 = fmaf(W.w2[0][2], aA0, fmaf(W.w2[1][2], aA1, W.b2v[2]));
    float yB2 = fmaf(W.w2[0][2], aB0, fmaf(W.w2[1][2], aB1, W.b2v[2]));
    float uA0 = fmaf(-aA0, aA0, 1.0f), uA1 = fmaf(-aA1, aA1, 1.0f);
    float uB0 = fmaf(-aB0, aB0, 1.0f), uB1 = fmaf(-aB1, aB1, 1.0f);
    float sA = fmaf(g0, uA0, g1 * uA1);
    float sB = fmaf(g0, uB0, g1 * uB1);
    va0 = red16(p * yA0); vb0 = red16(p * yB0);
    va1 = red16(p * yA1); vb1 = red16(p * yB1);
    va2 = red16(p * yA2); vb2 = red16(p * yB2);
    dA = p * sA; dB = p * sB;
}

// One full super-step: RK2 midpoint with fused mid/node v+div. 2 paired evals.
__device__ __forceinline__ void compute_step2(const WReg& W,
        float p12, float p1,
        float& XA0, float& XA1, float& XA2, float& XB0, float& XB1, float& XB2,
        float& vAa0, float& vAa1, float& vAa2, float& vAb0, float& vAb1, float& vAb2,
        float& dpA, float& dpB, float& div_acc, float& loss1p) {
    float g0 = fmaf(W.w2[0][0], W.w1[0][0], fmaf(W.w2[0][1], W.w1[0][1], W.w2[0][2] * W.w1[0][2]));
    float g1 = fmaf(W.w2[1][0], W.w1[1][0], fmaf(W.w2[1][1], W.w1[1][1], W.w2[1][2] * W.w1[1][2]));
    const float hh = H_ * 0.5f;

    // mid eval (fused v+div) at the RK2 stage state X0 + H/2*vA: vB = K2, d_mid
    float vBa0, vBa1, vBa2, vBb0, vBb1, vBb2, dmA, dmB;
    v_div_eval2(W, p12, g0, g1,
                fmaf(hh, vAa0, XA0), fmaf(hh, vAa1, XA1), fmaf(hh, vAa2, XA2),
                fmaf(hh, vAb0, XB0), fmaf(hh, vAb1, XB1), fmaf(hh, vAb2, XB2),
                vBa0, vBa1, vBa2, vBb0, vBb1, vBb2, dmA, dmB);
    // midpoint method: X1 = X0 + H*K2
    XA0 = fmaf(H_, vBa0, XA0);
    XA1 = fmaf(H_, vBa1, XA1);
    XA2 = fmaf(H_, vBa2, XA2);
    XB0 = fmaf(H_, vBb0, XB0);
    XB1 = fmaf(H_, vBb1, XB1);
    XB2 = fmaf(H_, vBb2, XB2);

    // node eval (fused v+div) at (X1, tn+H): vC, d_end; vC also = next step's K1
    float vCa0, vCa1, vCa2, vCb0, vCb1, vCb2, deA, deB;
    v_div_eval2(W, p1, g0, g1, XA0, XA1, XA2, XB0, XB1, XB2,
                vCa0, vCa1, vCa2, vCb0, vCb1, vCb2, deA, deB);

    // Simpson for lnRo over [tn, tn+H] (scaled by -H/6 at the end)
    div_acc += (dpA + 4.0f * dmA + deA) + (dpB + 4.0f * dmB + deB);
    dpA = deA; dpB = deB;                      // = d0 of next step
    loss1p += (vAa0 * vAa0 + vAa1 * vAa1 + vAa2 * vAa2)
            + 4.0f * (vBa0 * vBa0 + vBa1 * vBa1 + vBa2 * vBa2)
            + (vCa0 * vCa0 + vCa1 * vCa1 + vCa2 * vCa2)
            + (vAb0 * vAb0 + vAb1 * vAb1 + vAb2 * vAb2)
            + 4.0f * (vBb0 * vBb0 + vBb1 * vBb1 + vBb2 * vBb2)
            + (vCb0 * vCb0 + vCb1 * vCb1 + vCb2 * vCb2);
    vAa0 = vCa0; vAa1 = vCa1; vAa2 = vCa2;
    vAb0 = vCb0; vAb1 = vCb1; vAb2 = vCb2;
}

__global__ void __launch_bounds__(256)
loss_main_kernel(const float* __restrict__ x,
                 const float* __restrict__ W1, const float* __restrict__ b1,
                 const float* __restrict__ W2, const float* __restrict__ b2,
                 double* __restrict__ ws) {
    int gid = blockIdx.x * blockDim.x + threadIdx.x;
    int rA  = gid >> 4;       // sample A; sample B = rA + 4096
    int sub = gid & 15;
    int ii  = sub >> 3;       // basis half: 0 -> basis k, 1 -> basis k+1
    int j   = sub & 7;        // unit-tasks {2j, 2j+1}

    // ---- per-lane constant task offsets (within a step's 3-block window)
    int tauA = 2 * j, tauB = 2 * j + 1;
    bool padB = (tauB >= 15);
    int tB  = padB ? 0 : tauB;
    int lA  = tauA / 5, hA = tauA - 5 * lA;
    int lB  = tB / 5,   hB = tB - 5 * lB;
    int bA  = ii * 3 + lA, bB = ii * 3 + lB;
    int o1a = bA * 15 + hA * 3, o1b = bB * 15 + hB * 3;
    int oba = bA * 5 + hA,      obb = bB * 5 + hB;
    int o2a = bA * 15 + hA,     o2b = bB * 15 + hB;
    bool ab2 = (j < 3);
    int ob2 = (ii * 3 + (ab2 ? j : 0)) * 3;

    // ---- hat-basis weights: exact per-eval constants (w = 10t - k)
    float iif = (float)ii;
    float p12 = 0.5f;
    float p1  = iif;
    float p0  = 1.0f - iif;

    float XA0 = x[rA * 3 + 0], XA1 = x[rA * 3 + 1], XA2 = x[rA * 3 + 2];
    int rB = rA + 4096;
    float XB0 = x[rB * 3 + 0], XB1 = x[rB * 3 + 1], XB2 = x[rB * 3 + 2];

    float klbase = -0.5f * (XA0 * XA0 + XA1 * XA1 + XA2 * XA2)
                 - 0.5f * (XB0 * XB0 + XB1 * XB1 + XB2 * XB2);  // lnRo0 minus const
    float loss1p = 0.0f, div_acc = 0.0f;

    const float* pW1 = W1;
    const float* pB1 = b1;
    const float* pW2 = W2;
    const float* pB2 = b2;

    WReg A, B;
    load_step(A, pW1, pB1, pW2, pB2, o1a, o1b, oba, obb, o2a, o2b, ob2, padB, ab2);

    // initial eval at t=0: vA (reduced) + d0 partials
    float g0A = fmaf(A.w2[0][0], A.w1[0][0], fmaf(A.w2[0][1], A.w1[0][1], A.w2[0][2] * A.w1[0][2]));
    float g1A = fmaf(A.w2[1][0], A.w1[1][0], fmaf(A.w2[1][1], A.w1[1][1], A.w2[1][2] * A.w1[1][2]));
    float vAa0, vAa1, vAa2, vAb0, vAb1, vAb2, dpA, dpB;
    v_div_eval2(A, p0, g0A, g1A, XA0, XA1, XA2, XB0, XB1, XB2,
                vAa0, vAa1, vAa2, vAb0, vAb1, vAb2, dpA, dpB);

    #pragma unroll 1
    for (int kk = 0; kk < 5; ++kk) {
        // prefetch step 2kk+1 into B
        load_step(B, pW1 + 45, pB1 + 15, pW2 + 45, pB2 + 9,
                  o1a, o1b, oba, obb, o2a, o2b, ob2, padB, ab2);
        compute_step2(A, p12, p1,
                      XA0, XA1, XA2, XB0, XB1, XB2,
                      vAa0, vAa1, vAa2, vAb0, vAb1, vAb2,
                      dpA, dpB, div_acc, loss1p);
        // prefetch step 2kk+2 into A (last iter: harmless reload of step 9)
        const float* qW1 = pW1 + ((kk < 4) ? 90 : 45);
        const float* qB1 = pB1 + ((kk < 4) ? 30 : 15);
        const float* qW2 = pW2 + ((kk < 4) ? 90 : 45);
        const float* qB2 = pB2 + ((kk < 4) ? 18 : 9);
        load_step(A, qW1, qB1, qW2, qB2,
                  o1a, o1b, oba, obb, o2a, o2b, ob2, padB, ab2);
        compute_step2(B, p12, p1,
                      XA0, XA1, XA2, XB0, XB1, XB2,
                      vAa0, vAa1, vAa2, vAb0, vAb1, vAb2,
                      dpA, dpB, div_acc, loss1p);
        pW1 += 90; pB1 += 30; pW2 += 90; pB2 += 18;
    }

    // KL per sample-pair: (lnRo0 - lnr1) terms; the 3*log(2pi) constants cancel.
    float eA0 = XA0 - 1.0f, eA1 = XA1 - 1.0f, eA2 = XA2 - 1.0f;
    float eB0 = XB0 - 1.0f, eB1 = XB1 - 1.0f, eB2 = XB2 - 1.0f;
    float lnr1 = -0.5f * (eA0 * eA0 + eA1 * eA1 + eA2 * eA2)
               - 0.5f * (eB0 * eB0 + eB1 * eB1 + eB2 * eB2);
    float klp = ((threadIdx.x & 15) == 0) ? (klbase - lnr1) : 0.0f;
    klp = fmaf(-H6_, div_acc, klp);
    if ((threadIdx.x & 15) != 0) loss1p = 0.0f;

    #pragma unroll
    for (int off = 1; off < 64; off <<= 1) {    // once per kernel: shfl is fine here
        loss1p += __shfl_xor(loss1p, off);
        klp    += __shfl_xor(klp, off);
    }
    if ((threadIdx.x & 63) == 0) {
        int wid = gid >> 6;
        ws[wid]          = (double)loss1p;
        ws[NWAVES + wid] = (double)klp;
    }
}

__global__ void __launch_bounds__(64)
finalize_kernel(const double* __restrict__ ws, float* __restrict__ out) {
    int lane = threadIdx.x;
    double l1 = 0.0, kl = 0.0;
    #pragma unroll
    for (int j = 0; j < NWAVES / 64; ++j) {
        l1 += ws[lane + j * 64];
        kl += ws[NWAVES + lane + j * 64];
    }
    #pragma unroll
    for (int off = 1; off < 64; off <<= 1) {
        l1 += __shfl_xor(l1, off);
        kl += __shfl_xor(kl, off);
    }
    if (lane == 0) {
        double l1s = (double)H_ / (6.0 * (double)R_) * l1;
        double kls = kl / (double)R_;   // 3*log(2pi) constants canceled exactly
        float l1f = (float)l1s;
        float klf = (float)kls;
        out[0] = l1f + klf;   // loss  (loss_F == 0)
        out[1] = l1f;         // loss1
        out[2] = klf;         // loss_KL
        out[3] = 0.0f;        // loss_F
    }
}

extern "C" void kernel_launch(void* const* d_in, const int* in_sizes, int n_in,
                              void* d_out, int out_size, void* d_ws, size_t ws_size,
                              hipStream_t stream) {
    const float* x  = (const float*)d_in[0];
    const float* W1 = (const float*)d_in[1];
    const float* b1 = (const float*)d_in[2];
    const float* W2 = (const float*)d_in[3];
    const float* b2 = (const float*)d_in[4];
    double* ws = (double*)d_ws;   // [0..1023]=loss1 wave partials, [1024..2047]=KL
    float* out = (float*)d_out;

    // 4096 sample-pairs x 16 lanes = 65536 threads = 256 blocks x 256
    loss_main_kernel<<<256, 256, 0, stream>>>(x, W1, b1, W2, b2, ws);
    finalize_kernel<<<1, 64, 0, stream>>>(ws, out);
}